// Round 4
// baseline (347.889 us; speedup 1.0000x reference)
//
#include <hip/hip_runtime.h>
#include <hip/hip_bf16.h>

// FHE attention, B=2 S=4096 D=768 fp32.
// All stages as one canonical bf16 MFMA GEMM  C = scale*(A @ B^T) with the
// m97-verified structure: 128x128 tile, BK=32, 4 waves (2x2), 4x4 frags/wave,
// global_load_lds width=16 staging into linear LDS, 16 MFMA/k-iter/wave.
// Q|K projections merged (N=1536, contiguous [Wq;Wk]); scales folded: proj
// unscaled, QK^T epilogue scale = 1e-3. V^T = Wv @ x^T so PV is also A@B^T.

typedef __attribute__((ext_vector_type(8))) __bf16 bf16x8;
typedef __attribute__((ext_vector_type(4))) float f32x4;
typedef __attribute__((ext_vector_type(4))) float float4v;
typedef __attribute__((ext_vector_type(8))) unsigned short u16x8;
typedef __attribute__((ext_vector_type(4))) unsigned short u16x4;

__device__ inline unsigned short f2bf(float f) {
    union { float f; unsigned int u; } v; v.f = f;
    unsigned int r = v.u + 0x7FFFu + ((v.u >> 16) & 1u);  // RNE
    return (unsigned short)(r >> 16);
}

__global__ __launch_bounds__(256) void cvt_f32_bf16(const float* __restrict__ in,
                                                    unsigned short* __restrict__ out,
                                                    int n4) {
    int i = blockIdx.x * 256 + threadIdx.x;
    if (i < n4) {
        float4v v = *(const float4v*)(in + (size_t)i * 4);
        u16x4 h;
        h[0] = f2bf(v[0]); h[1] = f2bf(v[1]); h[2] = f2bf(v[2]); h[3] = f2bf(v[3]);
        *(u16x4*)(out + (size_t)i * 4) = h;
    }
}

__device__ inline void gld16(const void* g, void* l) {
    __builtin_amdgcn_global_load_lds(
        (const __attribute__((address_space(1))) unsigned int*)g,
        (__attribute__((address_space(3))) unsigned int*)l, 16, 0, 0);
}

// C[M,N] = scale * (A[M,K] @ B[N,K]^T); optional poly epilogue y = c*c + c.
// blockIdx.z batches with element strides szA/szB/szC. Grid covers M,N exactly.
template <bool POLY, typename TO>
__global__ __launch_bounds__(256) void gemm_bt(const unsigned short* __restrict__ A,
                                               const unsigned short* __restrict__ B,
                                               TO* __restrict__ C,
                                               int K, int lda, int ldb, int ldc,
                                               float scale,
                                               long long szA, long long szB, long long szC) {
    __shared__ __align__(16) unsigned short As[128 * 32];
    __shared__ __align__(16) unsigned short Bs[128 * 32];

    const int t = threadIdx.x;
    const int l = t & 63;
    const int wid = t >> 6;
    const int m0 = blockIdx.y * 128;
    const int n0 = blockIdx.x * 128;
    A += (size_t)blockIdx.z * szA;
    B += (size_t)blockIdx.z * szB;
    C += (size_t)blockIdx.z * szC;

    const int wr = wid >> 1, wc = wid & 1;       // wave's 64x64 quadrant
    const int lrow = l & 15, kslot = l >> 4;

    // Staging: wave wid owns tile rows [wid*32, wid*32+32) as two 1KB segments.
    // Lane l supplies 16B; HW writes LDS linearly at segbase + l*16
    // (elem wid*1024 + l*8 -> row wid*32 + l/4, col (l&3)*8) matching the
    // per-lane global address below. [m104: dest is wave-uniform base + lane*16]
    const int srow = wid * 32 + (l >> 2);
    const int scol = (l & 3) * 8;
    const unsigned short* Ag = A + (size_t)(m0 + srow) * lda + scol;
    const unsigned short* Bg = B + (size_t)(n0 + srow) * ldb + scol;
    unsigned short* lA = As + wid * 1024;
    unsigned short* lB = Bs + wid * 1024;

    f32x4 acc[4][4] = {};

    for (int k0 = 0; k0 < K; k0 += 32) {
        gld16(Ag + k0, lA);
        gld16(Ag + k0 + (size_t)16 * lda, lA + 512);
        gld16(Bg + k0, lB);
        gld16(Bg + k0 + (size_t)16 * ldb, lB + 512);
        __syncthreads();  // compiler drains vmcnt before barrier

        bf16x8 af[4], bfr[4];
#pragma unroll
        for (int mi = 0; mi < 4; ++mi) {
            u16x8 v = *(const u16x8*)(As + (wr * 64 + mi * 16 + lrow) * 32 + kslot * 8);
            af[mi] = __builtin_bit_cast(bf16x8, v);
        }
#pragma unroll
        for (int ni = 0; ni < 4; ++ni) {
            u16x8 v = *(const u16x8*)(Bs + (wc * 64 + ni * 16 + lrow) * 32 + kslot * 8);
            bfr[ni] = __builtin_bit_cast(bf16x8, v);
        }
#pragma unroll
        for (int mi = 0; mi < 4; ++mi)
#pragma unroll
            for (int ni = 0; ni < 4; ++ni)
                acc[mi][ni] = __builtin_amdgcn_mfma_f32_16x16x32_bf16(af[mi], bfr[ni], acc[mi][ni], 0, 0, 0);
        __syncthreads();
    }

    // C/D layout: col = lane&15, row = (lane>>4)*4 + r  [guide §3, m89-verified]
#pragma unroll
    for (int mi = 0; mi < 4; ++mi) {
        int rbase = m0 + wr * 64 + mi * 16 + kslot * 4;
#pragma unroll
        for (int ni = 0; ni < 4; ++ni) {
            int col = n0 + wc * 64 + ni * 16 + lrow;
#pragma unroll
            for (int r = 0; r < 4; ++r) {
                float v = acc[mi][ni][r] * scale;
                if constexpr (POLY) v = v * v + v;
                if constexpr (sizeof(TO) == 2)
                    C[(size_t)(rbase + r) * ldc + col] = f2bf(v);
                else
                    C[(size_t)(rbase + r) * ldc + col] = v;
            }
        }
    }
}

extern "C" void kernel_launch(void* const* d_in, const int* in_sizes, int n_in,
                              void* d_out, int out_size, void* d_ws, size_t ws_size,
                              hipStream_t stream) {
    const float* x  = (const float*)d_in[0];  // [2,4096,768]
    const float* Wq = (const float*)d_in[1];  // [768,768]
    const float* Wk = (const float*)d_in[2];
    const float* Wv = (const float*)d_in[3];
    const float* Wo = (const float*)d_in[4];
    float* out = (float*)d_out;

    const int BS = 8192, S = 4096, D = 768, D2 = 1536;
    unsigned short* ws = (unsigned short*)d_ws;
    size_t o = 0;
    unsigned short* QK   = ws + o; o += (size_t)BS * D2;  // [8192][1536] = [Q|K]
    unsigned short* Vt   = ws + o; o += (size_t)BS * D;   // [768][8192]
    unsigned short* Wqkb = ws + o; o += (size_t)D2 * D;   // [Wq;Wk] bf16
    unsigned short* Wvb  = ws + o; o += (size_t)D * D;
    unsigned short* Wob  = ws + o; o += (size_t)D * D;
    unsigned short* xb   = ws + o; o += (size_t)BS * D;   // dead after Vt -> AO
    unsigned short* P    = ws + o;                        // [nb][4096][4096]
    unsigned short* AO   = xb;

    const bool batched = ws_size >= (o + 2ull * S * S) * 2ull;

    dim3 blk(256);
    cvt_f32_bf16<<<dim3(BS * D / 1024), blk, 0, stream>>>(x, xb, BS * D / 4);
    cvt_f32_bf16<<<dim3(D * D / 1024), blk, 0, stream>>>(Wq, Wqkb, D * D / 4);
    cvt_f32_bf16<<<dim3(D * D / 1024), blk, 0, stream>>>(Wk, Wqkb + (size_t)D * D, D * D / 4);
    cvt_f32_bf16<<<dim3(D * D / 1024), blk, 0, stream>>>(Wv, Wvb, D * D / 4);
    cvt_f32_bf16<<<dim3(D * D / 1024), blk, 0, stream>>>(Wo, Wob, D * D / 4);

    // [Q|K] = xb @ [Wq;Wk]^T  (M=8192, N=1536, K=768), scales folded downstream
    gemm_bt<false, unsigned short><<<dim3(D2 / 128, BS / 128, 1), blk, 0, stream>>>(
        xb, Wqkb, QK, D, D, D, D2, 1.0f, 0, 0, 0);
    // V^T = Wv @ x^T  (M=768, N=8192, K=768), Vt[d][b*4096+s]
    gemm_bt<false, unsigned short><<<dim3(BS / 128, D / 128, 1), blk, 0, stream>>>(
        Wvb, xb, Vt, D, D, D, BS, 1.0f, 0, 0, 0);

    if (batched) {
        // P = poly(1e-3 * Q @ K^T) per batch  (M=N=4096, K=768)
        gemm_bt<true, unsigned short><<<dim3(S / 128, S / 128, 2), blk, 0, stream>>>(
            QK, QK + D, P, D, D2, D2, S, 1e-3f,
            (long long)S * D2, (long long)S * D2, (long long)S * S);
        // AO = P @ Vt_b^T  (M=4096, N=768, K=4096)
        gemm_bt<false, unsigned short><<<dim3(D / 128, S / 128, 2), blk, 0, stream>>>(
            P, Vt, AO, S, S, BS, D, 1.0f,
            (long long)S * S, (long long)S, (long long)S * D);
    } else {
        for (int b = 0; b < 2; ++b) {
            gemm_bt<true, unsigned short><<<dim3(S / 128, S / 128, 1), blk, 0, stream>>>(
                QK + (size_t)b * S * D2, QK + (size_t)b * S * D2 + D, P,
                D, D2, D2, S, 1e-3f, 0, 0, 0);
            gemm_bt<false, unsigned short><<<dim3(D / 128, S / 128, 1), blk, 0, stream>>>(
                P, Vt + (size_t)b * S, AO + (size_t)b * S * D, S, S, BS, D, 1.0f, 0, 0, 0);
        }
    }

    // out = 0.1 * AO @ Wo^T  (M=8192, N=768, K=768), fp32 out
    gemm_bt<false, float><<<dim3(D / 128, BS / 128, 1), blk, 0, stream>>>(
        AO, Wob, out, D, D, D, D, 0.1f, 0, 0, 0);
}

// Round 5
// 330.812 us; speedup vs baseline: 1.0516x; 1.0516x over previous
//
#include <hip/hip_runtime.h>
#include <hip/hip_bf16.h>

// FHE attention, B=2 S=4096 D=768 fp32.
// out = 0.1*(P @ VW), P = poly(1e-3 * (x Wq^T)(x Wk^T)^T), VW = x@(Wo@Wv)^T.
// The Wo projection is algebraically folded into the V projection (Wov=Wo@Wv),
// eliminating one 19.3 GF GEMM. PV is split-K=2 (768 blocks = 3/CU) with bf16
// partials in the dead QK buffer + a tiny fused reduce(0.1x) to fp32 out.
// All GEMMs: m97 structure (128x128 tile, BK=32, 4 waves, global_load_lds w16).

typedef __attribute__((ext_vector_type(8))) __bf16 bf16x8;
typedef __attribute__((ext_vector_type(4))) float f32x4;
typedef __attribute__((ext_vector_type(4))) float float4v;
typedef __attribute__((ext_vector_type(8))) unsigned short u16x8;
typedef __attribute__((ext_vector_type(4))) unsigned short u16x4;

__device__ inline unsigned short f2bf(float f) {
    union { float f; unsigned int u; } v; v.f = f;
    unsigned int r = v.u + 0x7FFFu + ((v.u >> 16) & 1u);  // RNE
    return (unsigned short)(r >> 16);
}
__device__ inline float bf2f(unsigned short h) {
    union { unsigned int u; float f; } v; v.u = ((unsigned int)h) << 16;
    return v.f;
}

__global__ __launch_bounds__(256) void cvt_f32_bf16(const float* __restrict__ in,
                                                    unsigned short* __restrict__ out,
                                                    int n4) {
    int i = blockIdx.x * 256 + threadIdx.x;
    if (i < n4) {
        float4v v = *(const float4v*)(in + (size_t)i * 4);
        u16x4 h;
        h[0] = f2bf(v[0]); h[1] = f2bf(v[1]); h[2] = f2bf(v[2]); h[3] = f2bf(v[3]);
        *(u16x4*)(out + (size_t)i * 4) = h;
    }
}

// outT[c][r] = bf16(in[r][c]), n x n fp32 -> bf16 transposed (n=768)
__global__ __launch_bounds__(256) void cvt_t_f32_bf16(const float* __restrict__ in,
                                                      unsigned short* __restrict__ outT,
                                                      int n) {
    __shared__ float tile[32][33];
    int c0 = blockIdx.x * 32, r0 = blockIdx.y * 32;
    int tx = threadIdx.x & 31, ty = threadIdx.x >> 5;  // 8 rows per pass
#pragma unroll
    for (int j = 0; j < 4; ++j)
        tile[ty + 8 * j][tx] = in[(size_t)(r0 + ty + 8 * j) * n + c0 + tx];
    __syncthreads();
#pragma unroll
    for (int j = 0; j < 4; ++j)
        outT[(size_t)(c0 + ty + 8 * j) * n + r0 + tx] = f2bf(tile[tx][ty + 8 * j]);
}

// out = 0.1f * (bf2f(p0) + bf2f(p1)), 8 elems/thread
__global__ __launch_bounds__(256) void reduce2_scale(const unsigned short* __restrict__ p0,
                                                     const unsigned short* __restrict__ p1,
                                                     float* __restrict__ out, int n8) {
    int i = blockIdx.x * 256 + threadIdx.x;
    if (i < n8) {
        u16x8 a = *(const u16x8*)(p0 + (size_t)i * 8);
        u16x8 b = *(const u16x8*)(p1 + (size_t)i * 8);
        float4v o0, o1;
#pragma unroll
        for (int j = 0; j < 4; ++j) {
            o0[j] = 0.1f * (bf2f(a[j]) + bf2f(b[j]));
            o1[j] = 0.1f * (bf2f(a[4 + j]) + bf2f(b[4 + j]));
        }
        *(float4v*)(out + (size_t)i * 8) = o0;
        *(float4v*)(out + (size_t)i * 8 + 4) = o1;
    }
}

__device__ inline void gld16(const void* g, void* l) {
    __builtin_amdgcn_global_load_lds(
        (const __attribute__((address_space(1))) unsigned int*)g,
        (__attribute__((address_space(3))) unsigned int*)l, 16, 0, 0);
}

// C[M,N] = scale * (A[M,K] @ B[N,K]^T); optional poly epilogue y = c*c + c.
// blockIdx.z: z1 = z>>ZS (strides sz*1), z2 = z & ((1<<ZS)-1) (strides sz*2).
template <bool POLY, typename TO, int ZS>
__global__ __launch_bounds__(256) void gemm_bt(const unsigned short* __restrict__ A,
                                               const unsigned short* __restrict__ B,
                                               TO* __restrict__ C,
                                               int K, int lda, int ldb, int ldc,
                                               float scale,
                                               long long szA1, long long szB1, long long szC1,
                                               long long szA2, long long szB2, long long szC2) {
    __shared__ __align__(16) unsigned short As[128 * 32];
    __shared__ __align__(16) unsigned short Bs[128 * 32];

    const int t = threadIdx.x;
    const int l = t & 63;
    const int wid = t >> 6;
    const int m0 = blockIdx.y * 128;
    const int n0 = blockIdx.x * 128;
    const int z = blockIdx.z;
    const int z1 = z >> ZS, z2 = z & ((1 << ZS) - 1);
    A += (size_t)z1 * szA1 + (size_t)z2 * szA2;
    B += (size_t)z1 * szB1 + (size_t)z2 * szB2;
    C += (size_t)z1 * szC1 + (size_t)z2 * szC2;

    const int wr = wid >> 1, wc = wid & 1;       // wave's 64x64 quadrant
    const int lrow = l & 15, kslot = l >> 4;

    // Staging [m104]: LDS dest is wave-uniform base + lane*16 (linear); per-lane
    // global addr chosen so elem wid*1024 + l*8 = row wid*32 + l/4, col (l&3)*8.
    const int srow = wid * 32 + (l >> 2);
    const int scol = (l & 3) * 8;
    const unsigned short* Ag = A + (size_t)(m0 + srow) * lda + scol;
    const unsigned short* Bg = B + (size_t)(n0 + srow) * ldb + scol;
    unsigned short* lA = As + wid * 1024;
    unsigned short* lB = Bs + wid * 1024;

    f32x4 acc[4][4] = {};

    for (int k0 = 0; k0 < K; k0 += 32) {
        gld16(Ag + k0, lA);
        gld16(Ag + k0 + (size_t)16 * lda, lA + 512);
        gld16(Bg + k0, lB);
        gld16(Bg + k0 + (size_t)16 * ldb, lB + 512);
        __syncthreads();  // compiler drains vmcnt before barrier

        bf16x8 af[4], bfr[4];
#pragma unroll
        for (int mi = 0; mi < 4; ++mi) {
            u16x8 v = *(const u16x8*)(As + (wr * 64 + mi * 16 + lrow) * 32 + kslot * 8);
            af[mi] = __builtin_bit_cast(bf16x8, v);
        }
#pragma unroll
        for (int ni = 0; ni < 4; ++ni) {
            u16x8 v = *(const u16x8*)(Bs + (wc * 64 + ni * 16 + lrow) * 32 + kslot * 8);
            bfr[ni] = __builtin_bit_cast(bf16x8, v);
        }
#pragma unroll
        for (int mi = 0; mi < 4; ++mi)
#pragma unroll
            for (int ni = 0; ni < 4; ++ni)
                acc[mi][ni] = __builtin_amdgcn_mfma_f32_16x16x32_bf16(af[mi], bfr[ni], acc[mi][ni], 0, 0, 0);
        __syncthreads();
    }

    // C/D layout: col = lane&15, row = (lane>>4)*4 + r  [guide §3, m89-verified]
#pragma unroll
    for (int mi = 0; mi < 4; ++mi) {
        int rbase = m0 + wr * 64 + mi * 16 + kslot * 4;
#pragma unroll
        for (int ni = 0; ni < 4; ++ni) {
            int col = n0 + wc * 64 + ni * 16 + lrow;
#pragma unroll
            for (int r = 0; r < 4; ++r) {
                float v = acc[mi][ni][r] * scale;
                if constexpr (POLY) v = v * v + v;
                if constexpr (sizeof(TO) == 2)
                    C[(size_t)(rbase + r) * ldc + col] = f2bf(v);
                else
                    C[(size_t)(rbase + r) * ldc + col] = v;
            }
        }
    }
}

extern "C" void kernel_launch(void* const* d_in, const int* in_sizes, int n_in,
                              void* d_out, int out_size, void* d_ws, size_t ws_size,
                              hipStream_t stream) {
    const float* x  = (const float*)d_in[0];  // [2,4096,768]
    const float* Wq = (const float*)d_in[1];  // [768,768]
    const float* Wk = (const float*)d_in[2];
    const float* Wv = (const float*)d_in[3];
    const float* Wo = (const float*)d_in[4];
    float* out = (float*)d_out;

    const int BS = 8192, S = 4096, D = 768, D2 = 1536;
    const long long SD = (long long)S * D, SS = (long long)S * S;
    unsigned short* ws = (unsigned short*)d_ws;
    size_t o = 0;
    unsigned short* QK   = ws + o; o += (size_t)BS * D2;  // [8192][1536]; later: PV partials
    unsigned short* VWt  = ws + o; o += (size_t)BS * D;   // [768][8192] = (x@Wov^T)^T
    unsigned short* Wqkb = ws + o; o += (size_t)D2 * D;   // [Wq;Wk] bf16
    unsigned short* Wob  = ws + o; o += (size_t)D * D;
    unsigned short* WvT  = ws + o; o += (size_t)D * D;    // Wv^T bf16
    unsigned short* Wovb = ws + o; o += (size_t)D * D;    // Wo@Wv bf16
    unsigned short* xb   = ws + o;                        // [8192][768]; dead after VWt/QKproj
    unsigned short* P    = xb;                            // overlaps xb
    const size_t oxb = o;

    // primary: P holds both batches (2*S*S after xb start)
    const bool batched = ws_size >= (oxb + 2ull * SS) * 2ull;

    dim3 blk(256);
    cvt_f32_bf16<<<dim3(BS * D / 1024), blk, 0, stream>>>(x, xb, BS * D / 4);
    cvt_f32_bf16<<<dim3(D * D / 1024), blk, 0, stream>>>(Wq, Wqkb, D * D / 4);
    cvt_f32_bf16<<<dim3(D * D / 1024), blk, 0, stream>>>(Wk, Wqkb + (size_t)D * D, D * D / 4);
    cvt_f32_bf16<<<dim3(D * D / 1024), blk, 0, stream>>>(Wo, Wob, D * D / 4);
    cvt_t_f32_bf16<<<dim3(D / 32, D / 32), blk, 0, stream>>>(Wv, WvT, D);

    // Wov = Wo @ Wv  (M=N=K=768)
    gemm_bt<false, unsigned short, 0><<<dim3(6, 6, 1), blk, 0, stream>>>(
        Wob, WvT, Wovb, D, D, D, D, 1.0f, 0, 0, 0, 0, 0, 0);
    // [Q|K] = xb @ [Wq;Wk]^T  (M=8192, N=1536, K=768); 0.1 scales folded into QKT
    gemm_bt<false, unsigned short, 0><<<dim3(D2 / 128, BS / 128, 1), blk, 0, stream>>>(
        xb, Wqkb, QK, D, D, D, D2, 1.0f, 0, 0, 0, 0, 0, 0);
    // VW^T = Wov @ x^T  (M=768, N=8192, K=768) -> VWt[d][b*4096+s]
    gemm_bt<false, unsigned short, 0><<<dim3(BS / 128, D / 128, 1), blk, 0, stream>>>(
        Wovb, xb, VWt, D, D, D, BS, 1.0f, 0, 0, 0, 0, 0, 0);

    const int KC = 2048;  // split-K chunk for PV
    if (batched) {
        // P = poly(1e-3 * Q @ K^T), both batches  (M=N=4096, K=768)
        gemm_bt<true, unsigned short, 0><<<dim3(S / 128, S / 128, 2), blk, 0, stream>>>(
            QK, QK + D, P, D, D2, D2, S, 1e-3f,
            (long long)S * D2, (long long)S * D2, SS, 0, 0, 0);
        // partials[kc][b] = P[b][:, kc*2048:+2048] @ VW[b]  -> QK buffer (bf16)
        // z = kc*2 + b: z1=kc strides (KC, KC, BS*D), z2=b strides (S*S, S, S*D)
        gemm_bt<false, unsigned short, 1><<<dim3(D / 128, S / 128, 4), blk, 0, stream>>>(
            P, VWt, QK, KC, S, BS, D, 1.0f,
            KC, KC, (long long)BS * D, SS, (long long)S, SD);
        // out = 0.1 * (part0 + part1), fp32
        reduce2_scale<<<dim3(BS * D / 8 / 256), blk, 0, stream>>>(
            QK, QK + (size_t)BS * D, out, BS * D / 8);
    } else {
        for (int b = 0; b < 2; ++b) {
            unsigned short* Pb = QK + (size_t)b * S * D2;  // dead QK half = partials
            gemm_bt<true, unsigned short, 0><<<dim3(S / 128, S / 128, 1), blk, 0, stream>>>(
                QK + (size_t)b * S * D2, QK + (size_t)b * S * D2 + D, P,
                D, D2, D2, S, 1e-3f, 0, 0, 0, 0, 0, 0);
            gemm_bt<false, unsigned short, 0><<<dim3(D / 128, S / 128, 2), blk, 0, stream>>>(
                P, VWt + (size_t)b * S, Pb, KC, S, BS, D, 1.0f,
                KC, KC, SD, 0, 0, 0);
            reduce2_scale<<<dim3(S * D / 8 / 256), blk, 0, stream>>>(
                Pb, Pb + SD, out + (size_t)b * SD, S * D / 8);
        }
    }
}

// Round 6
// 309.882 us; speedup vs baseline: 1.1226x; 1.0675x over previous
//
#include <hip/hip_runtime.h>
#include <hip/hip_bf16.h>

// FHE attention, B=2 S=4096 D=768 fp32.
// out = 0.1*(P @ VW), P = poly(1e-3 * (x Wq^T)(x Wk^T)^T), VW = x@(Wo@Wv)^T.
// Wo folded into V-projection (Wov = Wo@Wv). PV split-K=4 (1536 blocks = 6/CU)
// with bf16 partials + fused reduce(0.1x). T1 XCD swizzle on QKT/PV.
// All GEMMs: m97 structure (128x128, BK=32, 4 waves, global_load_lds w16).

typedef __attribute__((ext_vector_type(8))) __bf16 bf16x8;
typedef __attribute__((ext_vector_type(4))) float f32x4;
typedef __attribute__((ext_vector_type(4))) float float4v;
typedef __attribute__((ext_vector_type(8))) unsigned short u16x8;
typedef __attribute__((ext_vector_type(4))) unsigned short u16x4;

__device__ inline unsigned short f2bf(float f) {
    union { float f; unsigned int u; } v; v.f = f;
    unsigned int r = v.u + 0x7FFFu + ((v.u >> 16) & 1u);  // RNE
    return (unsigned short)(r >> 16);
}
__device__ inline float bf2f(unsigned short h) {
    union { unsigned int u; float f; } v; v.u = ((unsigned int)h) << 16;
    return v.f;
}

__global__ __launch_bounds__(256) void cvt_f32_bf16(const float* __restrict__ in,
                                                    unsigned short* __restrict__ out,
                                                    int n4) {
    int i = blockIdx.x * 256 + threadIdx.x;
    if (i < n4) {
        float4v v = *(const float4v*)(in + (size_t)i * 4);
        u16x4 h;
        h[0] = f2bf(v[0]); h[1] = f2bf(v[1]); h[2] = f2bf(v[2]); h[3] = f2bf(v[3]);
        *(u16x4*)(out + (size_t)i * 4) = h;
    }
}

// three same-size fp32->bf16 converts in one dispatch (blockIdx.y selects)
__global__ __launch_bounds__(256) void cvt3_f32_bf16(const float* __restrict__ a,
                                                     const float* __restrict__ b,
                                                     const float* __restrict__ c,
                                                     unsigned short* __restrict__ oa,
                                                     unsigned short* __restrict__ ob,
                                                     unsigned short* __restrict__ oc,
                                                     int n4) {
    const float* in = blockIdx.y == 0 ? a : blockIdx.y == 1 ? b : c;
    unsigned short* out = blockIdx.y == 0 ? oa : blockIdx.y == 1 ? ob : oc;
    int i = blockIdx.x * 256 + threadIdx.x;
    if (i < n4) {
        float4v v = *(const float4v*)(in + (size_t)i * 4);
        u16x4 h;
        h[0] = f2bf(v[0]); h[1] = f2bf(v[1]); h[2] = f2bf(v[2]); h[3] = f2bf(v[3]);
        *(u16x4*)(out + (size_t)i * 4) = h;
    }
}

// outT[c][r] = bf16(in[r][c]), n x n fp32 -> bf16 transposed (n=768)
__global__ __launch_bounds__(256) void cvt_t_f32_bf16(const float* __restrict__ in,
                                                      unsigned short* __restrict__ outT,
                                                      int n) {
    __shared__ float tile[32][33];
    int c0 = blockIdx.x * 32, r0 = blockIdx.y * 32;
    int tx = threadIdx.x & 31, ty = threadIdx.x >> 5;
#pragma unroll
    for (int j = 0; j < 4; ++j)
        tile[ty + 8 * j][tx] = in[(size_t)(r0 + ty + 8 * j) * n + c0 + tx];
    __syncthreads();
#pragma unroll
    for (int j = 0; j < 4; ++j)
        outT[(size_t)(c0 + ty + 8 * j) * n + r0 + tx] = f2bf(tile[tx][ty + 8 * j]);
}

__global__ __launch_bounds__(256) void reduce2_scale(const unsigned short* __restrict__ p0,
                                                     const unsigned short* __restrict__ p1,
                                                     float* __restrict__ out, int n8) {
    int i = blockIdx.x * 256 + threadIdx.x;
    if (i < n8) {
        u16x8 a = *(const u16x8*)(p0 + (size_t)i * 8);
        u16x8 b = *(const u16x8*)(p1 + (size_t)i * 8);
#pragma unroll
        for (int h = 0; h < 2; ++h) {
            float4v o;
#pragma unroll
            for (int j = 0; j < 4; ++j) o[j] = 0.1f * (bf2f(a[4 * h + j]) + bf2f(b[4 * h + j]));
            *(float4v*)(out + (size_t)i * 8 + 4 * h) = o;
        }
    }
}

// out[i] = 0.1*(sum of 4 bf16 partials at stride), i < n8*8
__global__ __launch_bounds__(256) void reduce4_scale(const unsigned short* __restrict__ p,
                                                     float* __restrict__ out,
                                                     long long stride, int n8) {
    int i = blockIdx.x * 256 + threadIdx.x;
    if (i < n8) {
        u16x8 a = *(const u16x8*)(p + (size_t)i * 8);
        u16x8 b = *(const u16x8*)(p + stride + (size_t)i * 8);
        u16x8 c = *(const u16x8*)(p + 2 * stride + (size_t)i * 8);
        u16x8 d = *(const u16x8*)(p + 3 * stride + (size_t)i * 8);
#pragma unroll
        for (int h = 0; h < 2; ++h) {
            float4v o;
#pragma unroll
            for (int j = 0; j < 4; ++j)
                o[j] = 0.1f * ((bf2f(a[4 * h + j]) + bf2f(b[4 * h + j])) +
                               (bf2f(c[4 * h + j]) + bf2f(d[4 * h + j])));
            *(float4v*)(out + (size_t)i * 8 + 4 * h) = o;
        }
    }
}

__device__ inline void gld16(const void* g, void* l) {
    __builtin_amdgcn_global_load_lds(
        (const __attribute__((address_space(1))) unsigned int*)g,
        (__attribute__((address_space(3))) unsigned int*)l, 16, 0, 0);
}

// Core 128x128 tile GEMM body: C = scale*(A @ B^T) for block (bx,by).
template <bool POLY, typename TO>
__device__ __forceinline__ void gemm_core(const unsigned short* __restrict__ A,
                                          const unsigned short* __restrict__ B,
                                          TO* __restrict__ C,
                                          int K, int lda, int ldb, int ldc, float scale,
                                          int bx, int by,
                                          unsigned short* As, unsigned short* Bs) {
    const int t = threadIdx.x;
    const int l = t & 63;
    const int wid = t >> 6;
    const int m0 = by * 128;
    const int n0 = bx * 128;

    const int wr = wid >> 1, wc = wid & 1;
    const int lrow = l & 15, kslot = l >> 4;

    // [m104] LDS dest = wave-uniform base + lane*16 (linear); per-lane global
    // addr: elem wid*1024 + l*8 -> row wid*32 + l/4, col (l&3)*8.
    const int srow = wid * 32 + (l >> 2);
    const int scol = (l & 3) * 8;
    const unsigned short* Ag = A + (size_t)(m0 + srow) * lda + scol;
    const unsigned short* Bg = B + (size_t)(n0 + srow) * ldb + scol;
    unsigned short* lA = As + wid * 1024;
    unsigned short* lB = Bs + wid * 1024;

    f32x4 acc[4][4] = {};

    for (int k0 = 0; k0 < K; k0 += 32) {
        gld16(Ag + k0, lA);
        gld16(Ag + k0 + (size_t)16 * lda, lA + 512);
        gld16(Bg + k0, lB);
        gld16(Bg + k0 + (size_t)16 * ldb, lB + 512);
        __syncthreads();

        bf16x8 af[4], bfr[4];
#pragma unroll
        for (int mi = 0; mi < 4; ++mi) {
            u16x8 v = *(const u16x8*)(As + (wr * 64 + mi * 16 + lrow) * 32 + kslot * 8);
            af[mi] = __builtin_bit_cast(bf16x8, v);
        }
#pragma unroll
        for (int ni = 0; ni < 4; ++ni) {
            u16x8 v = *(const u16x8*)(Bs + (wc * 64 + ni * 16 + lrow) * 32 + kslot * 8);
            bfr[ni] = __builtin_bit_cast(bf16x8, v);
        }
#pragma unroll
        for (int mi = 0; mi < 4; ++mi)
#pragma unroll
            for (int ni = 0; ni < 4; ++ni)
                acc[mi][ni] = __builtin_amdgcn_mfma_f32_16x16x32_bf16(af[mi], bfr[ni], acc[mi][ni], 0, 0, 0);
        __syncthreads();
    }

    // C/D layout: col = lane&15, row = (lane>>4)*4 + r  [m89-verified]
#pragma unroll
    for (int mi = 0; mi < 4; ++mi) {
        int rbase = m0 + wr * 64 + mi * 16 + kslot * 4;
#pragma unroll
        for (int ni = 0; ni < 4; ++ni) {
            int col = n0 + wc * 64 + ni * 16 + lrow;
#pragma unroll
            for (int r = 0; r < 4; ++r) {
                float v = acc[mi][ni][r] * scale;
                if constexpr (POLY) v = v * v + v;
                if constexpr (sizeof(TO) == 2)
                    C[(size_t)(rbase + r) * ldc + col] = f2bf(v);
                else
                    C[(size_t)(rbase + r) * ldc + col] = v;
            }
        }
    }
}

// Standalone GEMM. ZS: z split (z1=z>>ZS strides sz*1, z2 masked strides sz*2).
// SWZ: T1 XCD-aware block swizzle (requires gridDim.x*gridDim.y % 8 == 0).
template <bool POLY, typename TO, int ZS, bool SWZ>
__global__ __launch_bounds__(256) void gemm_bt(const unsigned short* __restrict__ A,
                                               const unsigned short* __restrict__ B,
                                               TO* __restrict__ C,
                                               int K, int lda, int ldb, int ldc,
                                               float scale,
                                               long long szA1, long long szB1, long long szC1,
                                               long long szA2, long long szB2, long long szC2) {
    __shared__ __align__(16) unsigned short As[128 * 32];
    __shared__ __align__(16) unsigned short Bs[128 * 32];

    int bx = blockIdx.x, by = blockIdx.y;
    if constexpr (SWZ) {
        int gx = gridDim.x;
        int nwg = gx * gridDim.y;
        int chunk = nwg >> 3;
        int flat = by * gx + bx;
        int f2 = (flat & 7) * chunk + (flat >> 3);
        bx = f2 % gx; by = f2 / gx;
    }
    const int z = blockIdx.z;
    const int z1 = z >> ZS, z2 = z & ((1 << ZS) - 1);
    gemm_core<POLY, TO>(A + (size_t)z1 * szA1 + (size_t)z2 * szA2,
                        B + (size_t)z1 * szB1 + (size_t)z2 * szB2,
                        C + (size_t)z1 * szC1 + (size_t)z2 * szC2,
                        K, lda, ldb, ldc, scale, bx, by, As, Bs);
}

// Merged projection dispatch: blocks [0,768) -> QK = xb@[Wq;Wk]^T (grid 12x64);
// blocks [768,1152) -> VWt = Wov@xb^T (grid 64x6).
__global__ __launch_bounds__(256) void gemm_proj2(const unsigned short* __restrict__ xb,
                                                  const unsigned short* __restrict__ Wqkb,
                                                  unsigned short* __restrict__ QK,
                                                  const unsigned short* __restrict__ Wovb,
                                                  unsigned short* __restrict__ VWt) {
    __shared__ __align__(16) unsigned short As[128 * 32];
    __shared__ __align__(16) unsigned short Bs[128 * 32];
    int bid = blockIdx.x;
    if (bid < 768) {
        gemm_core<false, unsigned short>(xb, Wqkb, QK, 768, 768, 768, 1536, 1.0f,
                                         bid % 12, bid / 12, As, Bs);
    } else {
        int r = bid - 768;
        gemm_core<false, unsigned short>(Wovb, xb, VWt, 768, 768, 768, 8192, 1.0f,
                                         r % 64, r / 64, As, Bs);
    }
}

extern "C" void kernel_launch(void* const* d_in, const int* in_sizes, int n_in,
                              void* d_out, int out_size, void* d_ws, size_t ws_size,
                              hipStream_t stream) {
    const float* x  = (const float*)d_in[0];  // [2,4096,768]
    const float* Wq = (const float*)d_in[1];  // [768,768]
    const float* Wk = (const float*)d_in[2];
    const float* Wv = (const float*)d_in[3];
    const float* Wo = (const float*)d_in[4];
    float* out = (float*)d_out;

    const int BS = 8192, S = 4096, D = 768, D2 = 1536;
    const long long SD = (long long)S * D, SS = (long long)S * S;
    const long long BSD = (long long)BS * D;
    unsigned short* ws = (unsigned short*)d_ws;
    size_t o = 0;
    unsigned short* QK   = ws + o; o += (size_t)BS * D2;  // [8192][1536]; later partial scratch
    unsigned short* VWt  = ws + o; o += (size_t)BS * D;   // [768][8192]
    unsigned short* Wqkb = ws + o; o += (size_t)D2 * D;
    unsigned short* Wob  = ws + o; o += (size_t)D * D;
    unsigned short* WvT  = ws + o; o += (size_t)D * D;
    unsigned short* Wovb = ws + o; o += (size_t)D * D;
    unsigned short* xb   = ws + o;                        // dead after projections
    unsigned short* P    = xb;                            // P overlaps xb
    const size_t oxb = o;
    unsigned short* Pp   = ws + oxb + (size_t)(2 * SS);   // tier-A partials [4][2][S][D]

    const size_t needA = (oxb + 2 * (size_t)SS + 4 * (size_t)BSD) * 2;
    const size_t needB = (oxb + 2 * (size_t)SS) * 2;

    dim3 blk(256);
    cvt_f32_bf16<<<dim3(BS * D / 1024), blk, 0, stream>>>(x, xb, BS * D / 4);
    cvt3_f32_bf16<<<dim3(D * D / 1024, 3), blk, 0, stream>>>(
        Wq, Wk, Wo, Wqkb, Wqkb + (size_t)D * D, Wob, D * D / 4);
    cvt_t_f32_bf16<<<dim3(D / 32, D / 32), blk, 0, stream>>>(Wv, WvT, D);

    // Wov = Wo @ Wv  (M=N=K=768)
    gemm_bt<false, unsigned short, 0, false><<<dim3(6, 6, 1), blk, 0, stream>>>(
        Wob, WvT, Wovb, D, D, D, D, 1.0f, 0, 0, 0, 0, 0, 0);
    // merged: [Q|K] = xb@[Wq;Wk]^T and VWt = Wov@xb^T
    gemm_proj2<<<dim3(1152), blk, 0, stream>>>(xb, Wqkb, QK, Wovb, VWt);

    if (ws_size >= needA) {
        // P = poly(1e-3 * Q @ K^T), both batches (M=N=4096, K=768), T1 swizzle
        gemm_bt<true, unsigned short, 0, true><<<dim3(S / 128, S / 128, 2), blk, 0, stream>>>(
            QK, QK + D, P, D, D2, D2, S, 1e-3f,
            (long long)S * D2, (long long)S * D2, SS, 0, 0, 0);
        // PV split-K=4: z = kc*2 + b; partials Pp[kc][b][s][d]
        const int KC = 1024;
        gemm_bt<false, unsigned short, 1, true><<<dim3(D / 128, S / 128, 8), blk, 0, stream>>>(
            P, VWt, Pp, KC, S, BS, D, 1.0f,
            KC, KC, BSD, SS, (long long)S, SD);
        reduce4_scale<<<dim3(BSD / 8 / 256), blk, 0, stream>>>(Pp, out, BSD, (int)(BSD / 8));
    } else if (ws_size >= needB) {
        gemm_bt<true, unsigned short, 0, true><<<dim3(S / 128, S / 128, 2), blk, 0, stream>>>(
            QK, QK + D, P, D, D2, D2, S, 1e-3f,
            (long long)S * D2, (long long)S * D2, SS, 0, 0, 0);
        const int KC = 2048;  // partials into dead QK buffer (2 fit)
        gemm_bt<false, unsigned short, 1, true><<<dim3(D / 128, S / 128, 4), blk, 0, stream>>>(
            P, VWt, QK, KC, S, BS, D, 1.0f,
            KC, KC, BSD, SS, (long long)S, SD);
        reduce2_scale<<<dim3(BSD / 8 / 256), blk, 0, stream>>>(
            QK, QK + (size_t)BSD, out, (int)(BSD / 8));
    } else {
        const int KC = 2048;
        for (int b = 0; b < 2; ++b) {
            unsigned short* Pb = QK + (size_t)b * S * D2;  // dead QK half
            gemm_bt<true, unsigned short, 0, true><<<dim3(S / 128, S / 128, 1), blk, 0, stream>>>(
                QK + (size_t)b * S * D2, QK + (size_t)b * S * D2 + D, P,
                D, D2, D2, S, 1e-3f, 0, 0, 0, 0, 0, 0);
            gemm_bt<false, unsigned short, 0, true><<<dim3(D / 128, S / 128, 2), blk, 0, stream>>>(
                P, VWt + (size_t)b * S, Pb, KC, S, BS, D, 1.0f,
                KC, KC, SD, 0, 0, 0);
            reduce2_scale<<<dim3(SD / 8 / 256), blk, 0, stream>>>(
                Pb, Pb + SD, out + (size_t)b * SD, (int)(SD / 8));
        }
    }
}

// Round 8
// 283.797 us; speedup vs baseline: 1.2258x; 1.0919x over previous
//
#include <hip/hip_runtime.h>
#include <hip/hip_bf16.h>

// FHE attention, B=2 S=4096 D=768 fp32.
// out = 0.1*(P @ VW), P = poly(1e-3 * (x Wq^T)(x Wk^T)^T), VW = x@(Wo@Wv)^T.
// Wo folded into V (Wov=Wo@Wv). All GEMMs: 128xTN tile, BK=64, 4 waves,
// global_load_lds w16 into LINEAR LDS with both-sides XOR swizzle
// (colblk16B ^= row&7; inverse-permuted global source per m201/rule-21),
// making ds_read_b128 bank-conflict-free. PV: TN=64, full K=4096, fp32 out
// directly (no split-K, no reduce pass). T1 XCD swizzle on PV only
// (QKT inputs are L3-resident; swizzle measured -11% there in R6).

typedef __attribute__((ext_vector_type(8))) __bf16 bf16x8;
typedef __attribute__((ext_vector_type(4))) float f32x4;
typedef __attribute__((ext_vector_type(4))) float float4v;
typedef __attribute__((ext_vector_type(8))) unsigned short u16x8;
typedef __attribute__((ext_vector_type(4))) unsigned short u16x4;

__device__ inline unsigned short f2bf(float f) {
    union { float f; unsigned int u; } v; v.f = f;
    unsigned int r = v.u + 0x7FFFu + ((v.u >> 16) & 1u);  // RNE
    return (unsigned short)(r >> 16);
}

__global__ __launch_bounds__(256) void cvt_f32_bf16(const float* __restrict__ in,
                                                    unsigned short* __restrict__ out,
                                                    int n4) {
    int i = blockIdx.x * 256 + threadIdx.x;
    if (i < n4) {
        float4v v = *(const float4v*)(in + (size_t)i * 4);
        u16x4 h;
        h[0] = f2bf(v[0]); h[1] = f2bf(v[1]); h[2] = f2bf(v[2]); h[3] = f2bf(v[3]);
        *(u16x4*)(out + (size_t)i * 4) = h;
    }
}

// three same-size fp32->bf16 converts in one dispatch (blockIdx.y selects)
__global__ __launch_bounds__(256) void cvt3_f32_bf16(const float* __restrict__ a,
                                                     const float* __restrict__ b,
                                                     const float* __restrict__ c,
                                                     unsigned short* __restrict__ oa,
                                                     unsigned short* __restrict__ ob,
                                                     unsigned short* __restrict__ oc,
                                                     int n4) {
    const float* in = blockIdx.y == 0 ? a : blockIdx.y == 1 ? b : c;
    unsigned short* out = blockIdx.y == 0 ? oa : blockIdx.y == 1 ? ob : oc;
    int i = blockIdx.x * 256 + threadIdx.x;
    if (i < n4) {
        float4v v = *(const float4v*)(in + (size_t)i * 4);
        u16x4 h;
        h[0] = f2bf(v[0]); h[1] = f2bf(v[1]); h[2] = f2bf(v[2]); h[3] = f2bf(v[3]);
        *(u16x4*)(out + (size_t)i * 4) = h;
    }
}

// outT[c][r] = bf16(in[r][c]), n x n fp32 -> bf16 transposed (n=768)
__global__ __launch_bounds__(256) void cvt_t_f32_bf16(const float* __restrict__ in,
                                                      unsigned short* __restrict__ outT,
                                                      int n) {
    __shared__ float tile[32][33];
    int c0 = blockIdx.x * 32, r0 = blockIdx.y * 32;
    int tx = threadIdx.x & 31, ty = threadIdx.x >> 5;
#pragma unroll
    for (int j = 0; j < 4; ++j)
        tile[ty + 8 * j][tx] = in[(size_t)(r0 + ty + 8 * j) * n + c0 + tx];
    __syncthreads();
#pragma unroll
    for (int j = 0; j < 4; ++j)
        outT[(size_t)(c0 + ty + 8 * j) * n + r0 + tx] = f2bf(tile[tx][ty + 8 * j]);
}

__device__ inline void gld16(const void* g, void* l) {
    __builtin_amdgcn_global_load_lds(
        (const __attribute__((address_space(1))) unsigned int*)g,
        (__attribute__((address_space(3))) unsigned int*)l, 16, 0, 0);
}

// Core: C[128 x TN] tile of scale*(A @ B^T), BK=64, 4 waves (2x2).
// LDS layout per operand: [rows][64] linear, but col-block (16B = 8 elems)
// XOR-swizzled: LDS[r][cb] holds global[r][cb ^ (r&7)]. Staged via
// global_load_lds (linear dest) with the per-lane GLOBAL col permuted by the
// same involution; ds_read_b128 applies the XOR on its address -> 8 lanes of
// a fragment hit 8 distinct 16B slots = conflict-free (2-way residual free).
template <int TN, bool POLY, typename TO>
__device__ __forceinline__ void gemm_core(const unsigned short* __restrict__ A,
                                          const unsigned short* __restrict__ B,
                                          TO* __restrict__ C,
                                          int K, int lda, int ldb, int ldc,
                                          float scale, int bx, int by,
                                          unsigned short* As, unsigned short* Bs) {
    constexpr int NR = TN / 32;            // B fragments per wave (col dir)
    const int t = threadIdx.x, l = t & 63, wid = t >> 6;
    const int m0 = by * 128, n0 = bx * TN;
    const int wr = wid >> 1, wc = wid & 1;
    const int lrow = l & 15, kslot = l >> 4;

    // staging lane constants: seg s covers 32 rows; lane l supplies
    // global (row = s*32 + wid*8 + (l>>3), colblk = (l&7) ^ ((l>>3)&7)).
    // LDS dest (wave-uniform): s*2048 + wid*512 elems; HW adds lane*16B.
    const int ce = (((l & 7) ^ ((l >> 3) & 7)) << 3);
    const unsigned short* Ag = A + (size_t)(m0 + wid * 8 + (l >> 3)) * lda + ce;
    const unsigned short* Bg = B + (size_t)(n0 + wid * 8 + (l >> 3)) * ldb + ce;

    f32x4 acc[4][NR] = {};

    for (int k0 = 0; k0 < K; k0 += 64) {
#pragma unroll
        for (int s = 0; s < 4; ++s)
            gld16(Ag + (size_t)(s * 32) * lda + k0, As + s * 2048 + wid * 512);
#pragma unroll
        for (int s = 0; s < TN / 32; ++s)
            gld16(Bg + (size_t)(s * 32) * ldb + k0, Bs + s * 2048 + wid * 512);
        __syncthreads();  // compiler drains vmcnt before barrier

        bf16x8 af[4][2], bfr[NR][2];
#pragma unroll
        for (int kk = 0; kk < 2; ++kk) {
#pragma unroll
            for (int mi = 0; mi < 4; ++mi) {
                int r = wr * 64 + mi * 16 + lrow;
                int j = (kk * 4 + kslot) ^ (r & 7);
                u16x8 v = *(const u16x8*)(As + r * 64 + j * 8);
                af[mi][kk] = __builtin_bit_cast(bf16x8, v);
            }
#pragma unroll
            for (int ni = 0; ni < NR; ++ni) {
                int r = wc * (TN / 2) + ni * 16 + lrow;
                int j = (kk * 4 + kslot) ^ (r & 7);
                u16x8 v = *(const u16x8*)(Bs + r * 64 + j * 8);
                bfr[ni][kk] = __builtin_bit_cast(bf16x8, v);
            }
        }
#pragma unroll
        for (int kk = 0; kk < 2; ++kk)
#pragma unroll
            for (int mi = 0; mi < 4; ++mi)
#pragma unroll
                for (int ni = 0; ni < NR; ++ni)
                    acc[mi][ni] = __builtin_amdgcn_mfma_f32_16x16x32_bf16(
                        af[mi][kk], bfr[ni][kk], acc[mi][ni], 0, 0, 0);
        __syncthreads();
    }

    // C/D layout: col = lane&15, row = (lane>>4)*4 + r  [m89-verified]
#pragma unroll
    for (int mi = 0; mi < 4; ++mi) {
        int rbase = m0 + wr * 64 + mi * 16 + kslot * 4;
#pragma unroll
        for (int ni = 0; ni < NR; ++ni) {
            int col = n0 + wc * (TN / 2) + ni * 16 + lrow;
#pragma unroll
            for (int r = 0; r < 4; ++r) {
                float v = acc[mi][ni][r] * scale;
                if constexpr (POLY) v = v * v + v;
                if constexpr (sizeof(TO) == 2)
                    C[(size_t)(rbase + r) * ldc + col] = f2bf(v);
                else
                    C[(size_t)(rbase + r) * ldc + col] = v;
            }
        }
    }
}

// Standalone GEMM; blockIdx.z batches via element strides. SWZ: T1 XCD swizzle
// (requires gridDim.x*gridDim.y % 8 == 0).
template <int TN, bool POLY, typename TO, bool SWZ>
__global__ __launch_bounds__(256) void gemm_bt(const unsigned short* __restrict__ A,
                                               const unsigned short* __restrict__ B,
                                               TO* __restrict__ C,
                                               int K, int lda, int ldb, int ldc,
                                               float scale,
                                               long long szA, long long szB, long long szC) {
    __shared__ __align__(16) unsigned short As[128 * 64];
    __shared__ __align__(16) unsigned short Bs[TN * 64];
    int bx = blockIdx.x, by = blockIdx.y;
    if constexpr (SWZ) {
        int gx = gridDim.x;
        int nwg = gx * gridDim.y;
        int chunk = nwg >> 3;
        int flat = by * gx + bx;
        int f2 = (flat & 7) * chunk + (flat >> 3);
        bx = f2 % gx; by = f2 / gx;
    }
    const size_t z = blockIdx.z;
    gemm_core<TN, POLY, TO>(A + z * szA, B + z * szB, C + z * szC,
                            K, lda, ldb, ldc, scale, bx, by, As, Bs);
}

// Merged projections: blocks [0,768) -> QK = xb@[Wq;Wk]^T (12x64);
// blocks [768,1152) -> VWt = Wov@xb^T (64x6).
__global__ __launch_bounds__(256) void gemm_proj2(const unsigned short* __restrict__ xb,
                                                  const unsigned short* __restrict__ Wqkb,
                                                  unsigned short* __restrict__ QK,
                                                  const unsigned short* __restrict__ Wovb,
                                                  unsigned short* __restrict__ VWt) {
    __shared__ __align__(16) unsigned short As[128 * 64];
    __shared__ __align__(16) unsigned short Bs[128 * 64];
    int bid = blockIdx.x;
    if (bid < 768) {
        gemm_core<128, false, unsigned short>(xb, Wqkb, QK, 768, 768, 768, 1536, 1.0f,
                                              bid % 12, bid / 12, As, Bs);
    } else {
        int r = bid - 768;
        gemm_core<128, false, unsigned short>(Wovb, xb, VWt, 768, 768, 768, 8192, 1.0f,
                                              r % 64, r / 64, As, Bs);
    }
}

extern "C" void kernel_launch(void* const* d_in, const int* in_sizes, int n_in,
                              void* d_out, int out_size, void* d_ws, size_t ws_size,
                              hipStream_t stream) {
    const float* x  = (const float*)d_in[0];  // [2,4096,768]
    const float* Wq = (const float*)d_in[1];  // [768,768]
    const float* Wk = (const float*)d_in[2];
    const float* Wv = (const float*)d_in[3];
    const float* Wo = (const float*)d_in[4];
    float* out = (float*)d_out;

    const int BS = 8192, S = 4096, D = 768, D2 = 1536;
    const long long SD = (long long)S * D, SS = (long long)S * S;
    unsigned short* ws = (unsigned short*)d_ws;
    size_t o = 0;
    unsigned short* QK   = ws + o; o += (size_t)BS * D2;  // [8192][1536] = [Q|K]
    unsigned short* VWt  = ws + o; o += (size_t)BS * D;   // [768][8192] = (x@Wov^T)^T
    unsigned short* Wqkb = ws + o; o += (size_t)D2 * D;
    unsigned short* Wob  = ws + o; o += (size_t)D * D;
    unsigned short* WvT  = ws + o; o += (size_t)D * D;
    unsigned short* Wovb = ws + o; o += (size_t)D * D;
    unsigned short* xb   = ws + o;                        // dead after projections
    unsigned short* P    = xb;                            // P overlaps xb
    const size_t oxb = o;

    const bool batched = ws_size >= (oxb + 2ull * SS) * 2ull;  // P both batches

    dim3 blk(256);
    cvt_f32_bf16<<<dim3(BS * D / 1024), blk, 0, stream>>>(x, xb, BS * D / 4);
    cvt3_f32_bf16<<<dim3(D * D / 1024, 3), blk, 0, stream>>>(
        Wq, Wk, Wo, Wqkb, Wqkb + (size_t)D * D, Wob, D * D / 4);
    cvt_t_f32_bf16<<<dim3(D / 32, D / 32), blk, 0, stream>>>(Wv, WvT, D);

    // Wov = Wo @ Wv  (M=N=K=768)
    gemm_bt<128, false, unsigned short, false><<<dim3(6, 6, 1), blk, 0, stream>>>(
        Wob, WvT, Wovb, D, D, D, D, 1.0f, 0, 0, 0);
    // merged: [Q|K] = xb@[Wq;Wk]^T and VWt = Wov@xb^T
    gemm_proj2<<<dim3(1152), blk, 0, stream>>>(xb, Wqkb, QK, Wovb, VWt);

    if (batched) {
        // P = poly(1e-3 * Q @ K^T), both batches (M=N=4096, K=768)
        gemm_bt<128, true, unsigned short, false><<<dim3(S / 128, S / 128, 2), blk, 0, stream>>>(
            QK, QK + D, P, D, D2, D2, S, 1e-3f,
            (long long)S * D2, (long long)S * D2, SS);
        // out = 0.1 * P @ VW  (M=4096, N=768, K=4096), fp32 out, no split-K.
        // 12x32x2 = 768 blocks = 3/CU, all resident. T1 swizzle for P L2 reuse.
        gemm_bt<64, false, float, true><<<dim3(D / 64, S / 128, 2), blk, 0, stream>>>(
            P, VWt, out, S, S, BS, D, 0.1f, SS, (long long)S, SD);
    } else {
        for (int b = 0; b < 2; ++b) {
            gemm_bt<128, true, unsigned short, false><<<dim3(S / 128, S / 128, 1), blk, 0, stream>>>(
                QK + (size_t)b * S * D2, QK + (size_t)b * S * D2 + D, P,
                D, D2, D2, S, 1e-3f, 0, 0, 0);
            gemm_bt<64, false, float, true><<<dim3(D / 64, S / 128, 1), blk, 0, stream>>>(
                P, VWt + (size_t)b * S, out + (size_t)b * SD, S, S, BS, D, 0.1f, 0, 0, 0);
        }
    }
}

// Round 9
// 269.858 us; speedup vs baseline: 1.2892x; 1.0517x over previous
//
#include <hip/hip_runtime.h>
#include <hip/hip_bf16.h>

// FHE attention, B=2 S=4096 D=768 fp32.
// out = 0.1*(P @ VW), P = poly(1e-3 * (x Wq^T)(x Wk^T)^T), VW = x@(Wo@Wv)^T.
// QK^T: 256x256 8-wave phased kernel (BK=64 pairs, counted-vmcnt pipeline,
// setprio, raw s_barrier) — T3/T4/T5 per regime-gate. Other GEMMs: 128-tile
// 2-barrier structure with conflict-free XOR swizzle (R8, measured 0 conflicts).

typedef __attribute__((ext_vector_type(8))) __bf16 bf16x8;
typedef __attribute__((ext_vector_type(4))) float f32x4;
typedef __attribute__((ext_vector_type(4))) float float4v;
typedef __attribute__((ext_vector_type(8))) unsigned short u16x8;
typedef __attribute__((ext_vector_type(4))) unsigned short u16x4;

__device__ inline unsigned short f2bf(float f) {
    union { float f; unsigned int u; } v; v.f = f;
    unsigned int r = v.u + 0x7FFFu + ((v.u >> 16) & 1u);  // RNE
    return (unsigned short)(r >> 16);
}

__global__ __launch_bounds__(256) void cvt_f32_bf16(const float* __restrict__ in,
                                                    unsigned short* __restrict__ out,
                                                    int n4) {
    int i = blockIdx.x * 256 + threadIdx.x;
    if (i < n4) {
        float4v v = *(const float4v*)(in + (size_t)i * 4);
        u16x4 h;
        h[0] = f2bf(v[0]); h[1] = f2bf(v[1]); h[2] = f2bf(v[2]); h[3] = f2bf(v[3]);
        *(u16x4*)(out + (size_t)i * 4) = h;
    }
}

__global__ __launch_bounds__(256) void cvt3_f32_bf16(const float* __restrict__ a,
                                                     const float* __restrict__ b,
                                                     const float* __restrict__ c,
                                                     unsigned short* __restrict__ oa,
                                                     unsigned short* __restrict__ ob,
                                                     unsigned short* __restrict__ oc,
                                                     int n4) {
    const float* in = blockIdx.y == 0 ? a : blockIdx.y == 1 ? b : c;
    unsigned short* out = blockIdx.y == 0 ? oa : blockIdx.y == 1 ? ob : oc;
    int i = blockIdx.x * 256 + threadIdx.x;
    if (i < n4) {
        float4v v = *(const float4v*)(in + (size_t)i * 4);
        u16x4 h;
        h[0] = f2bf(v[0]); h[1] = f2bf(v[1]); h[2] = f2bf(v[2]); h[3] = f2bf(v[3]);
        *(u16x4*)(out + (size_t)i * 4) = h;
    }
}

__global__ __launch_bounds__(256) void cvt_t_f32_bf16(const float* __restrict__ in,
                                                      unsigned short* __restrict__ outT,
                                                      int n) {
    __shared__ float tile[32][33];
    int c0 = blockIdx.x * 32, r0 = blockIdx.y * 32;
    int tx = threadIdx.x & 31, ty = threadIdx.x >> 5;
#pragma unroll
    for (int j = 0; j < 4; ++j)
        tile[ty + 8 * j][tx] = in[(size_t)(r0 + ty + 8 * j) * n + c0 + tx];
    __syncthreads();
#pragma unroll
    for (int j = 0; j < 4; ++j)
        outT[(size_t)(c0 + ty + 8 * j) * n + r0 + tx] = f2bf(tile[tx][ty + 8 * j]);
}

__device__ inline void gld16(const void* g, void* l) {
    __builtin_amdgcn_global_load_lds(
        (const __attribute__((address_space(1))) unsigned int*)g,
        (__attribute__((address_space(3))) unsigned int*)l, 16, 0, 0);
}

// ---------------- 128-tile kernel (R8, unchanged) ----------------
template <int TN, bool POLY, typename TO>
__device__ __forceinline__ void gemm_core(const unsigned short* __restrict__ A,
                                          const unsigned short* __restrict__ B,
                                          TO* __restrict__ C,
                                          int K, int lda, int ldb, int ldc,
                                          float scale, int bx, int by,
                                          unsigned short* As, unsigned short* Bs) {
    constexpr int NR = TN / 32;
    const int t = threadIdx.x, l = t & 63, wid = t >> 6;
    const int m0 = by * 128, n0 = bx * TN;
    const int wr = wid >> 1, wc = wid & 1;
    const int lrow = l & 15, kslot = l >> 4;

    const int ce = (((l & 7) ^ ((l >> 3) & 7)) << 3);
    const unsigned short* Ag = A + (size_t)(m0 + wid * 8 + (l >> 3)) * lda + ce;
    const unsigned short* Bg = B + (size_t)(n0 + wid * 8 + (l >> 3)) * ldb + ce;

    f32x4 acc[4][NR] = {};

    for (int k0 = 0; k0 < K; k0 += 64) {
#pragma unroll
        for (int s = 0; s < 4; ++s)
            gld16(Ag + (size_t)(s * 32) * lda + k0, As + s * 2048 + wid * 512);
#pragma unroll
        for (int s = 0; s < TN / 32; ++s)
            gld16(Bg + (size_t)(s * 32) * ldb + k0, Bs + s * 2048 + wid * 512);
        __syncthreads();

        bf16x8 af[4][2], bfr[NR][2];
#pragma unroll
        for (int kk = 0; kk < 2; ++kk) {
#pragma unroll
            for (int mi = 0; mi < 4; ++mi) {
                int r = wr * 64 + mi * 16 + lrow;
                int j = (kk * 4 + kslot) ^ (r & 7);
                u16x8 v = *(const u16x8*)(As + r * 64 + j * 8);
                af[mi][kk] = __builtin_bit_cast(bf16x8, v);
            }
#pragma unroll
            for (int ni = 0; ni < NR; ++ni) {
                int r = wc * (TN / 2) + ni * 16 + lrow;
                int j = (kk * 4 + kslot) ^ (r & 7);
                u16x8 v = *(const u16x8*)(Bs + r * 64 + j * 8);
                bfr[ni][kk] = __builtin_bit_cast(bf16x8, v);
            }
        }
#pragma unroll
        for (int kk = 0; kk < 2; ++kk)
#pragma unroll
            for (int mi = 0; mi < 4; ++mi)
#pragma unroll
                for (int ni = 0; ni < NR; ++ni)
                    acc[mi][ni] = __builtin_amdgcn_mfma_f32_16x16x32_bf16(
                        af[mi][kk], bfr[ni][kk], acc[mi][ni], 0, 0, 0);
        __syncthreads();
    }

#pragma unroll
    for (int mi = 0; mi < 4; ++mi) {
        int rbase = m0 + wr * 64 + mi * 16 + kslot * 4;
#pragma unroll
        for (int ni = 0; ni < NR; ++ni) {
            int col = n0 + wc * (TN / 2) + ni * 16 + lrow;
#pragma unroll
            for (int r = 0; r < 4; ++r) {
                float v = acc[mi][ni][r] * scale;
                if constexpr (POLY) v = v * v + v;
                if constexpr (sizeof(TO) == 2)
                    C[(size_t)(rbase + r) * ldc + col] = f2bf(v);
                else
                    C[(size_t)(rbase + r) * ldc + col] = v;
            }
        }
    }
}

template <int TN, bool POLY, typename TO, bool SWZ>
__global__ __launch_bounds__(256) void gemm_bt(const unsigned short* __restrict__ A,
                                               const unsigned short* __restrict__ B,
                                               TO* __restrict__ C,
                                               int K, int lda, int ldb, int ldc,
                                               float scale,
                                               long long szA, long long szB, long long szC) {
    __shared__ __align__(16) unsigned short As[128 * 64];
    __shared__ __align__(16) unsigned short Bs[TN * 64];
    int bx = blockIdx.x, by = blockIdx.y;
    if constexpr (SWZ) {
        int gx = gridDim.x;
        int nwg = gx * gridDim.y;
        int chunk = nwg >> 3;
        int flat = by * gx + bx;
        int f2 = (flat & 7) * chunk + (flat >> 3);
        bx = f2 % gx; by = f2 / gx;
    }
    const size_t z = blockIdx.z;
    gemm_core<TN, POLY, TO>(A + z * szA, B + z * szB, C + z * szC,
                            K, lda, ldb, ldc, scale, bx, by, As, Bs);
}

__global__ __launch_bounds__(256) void gemm_proj2(const unsigned short* __restrict__ xb,
                                                  const unsigned short* __restrict__ Wqkb,
                                                  unsigned short* __restrict__ QK,
                                                  const unsigned short* __restrict__ Wovb,
                                                  unsigned short* __restrict__ VWt) {
    __shared__ __align__(16) unsigned short As[128 * 64];
    __shared__ __align__(16) unsigned short Bs[128 * 64];
    int bid = blockIdx.x;
    if (bid < 768) {
        gemm_core<128, false, unsigned short>(xb, Wqkb, QK, 768, 768, 768, 1536, 1.0f,
                                              bid % 12, bid / 12, As, Bs);
    } else {
        int r = bid - 768;
        gemm_core<128, false, unsigned short>(Wovb, xb, VWt, 768, 768, 768, 8192, 1.0f,
                                              r % 64, r / 64, As, Bs);
    }
}

// ---------------- 256x256 8-wave phased QK^T kernel ----------------
// 512 thr = 8 waves (2M x 4N); wave tile 128x64; acc[8][4] f32x4.
// LDS (dynamic 128 KB): A[2][256][64] + B[2][256][64] bf16, XOR-swizzled
// (LDS[r][cb] = global[r][cb^(r&7)], staged linear-dest w/ inverse-permuted
// global source; ds_read_b128 conflict-free, measured 0 in R8 structure).
// Pipeline: pair P+1's 8 gld16 issued bunched at pair P phase 0 (WAR-safe:
// that buffer's reads retired before the preceding barrier); ONE
// s_waitcnt vmcnt(0) at pair end (counted discipline, never per-phase);
// raw s_barrier (no implicit drain); setprio(1) around 16-MFMA clusters.
template <bool POLY>
__global__ __launch_bounds__(512, 2) void gemm_qkt8(const unsigned short* __restrict__ A,
                                                    const unsigned short* __restrict__ B,
                                                    unsigned short* __restrict__ C,
                                                    int K, int lda, int ldb, int ldc,
                                                    float scale,
                                                    long long szA, long long szB, long long szC) {
    extern __shared__ __align__(16) unsigned short lds[];  // [A:2*16384][B:2*16384]
    const int t = threadIdx.x, l = t & 63, w = t >> 6;
    const int wm = w >> 2, wn = w & 3;
    const int m0 = blockIdx.y * 256, n0 = blockIdx.x * 256;
    const size_t z = blockIdx.z;
    A += z * szA; B += z * szB; C += z * szC;
    const int lrow = l & 15, kslot = l >> 4;
    const int jc = lrow & 7;
    const int arow = (wm * 128 + lrow) * 64;  // LDS elem base for A frags
    const int brow = (wn * 64 + lrow) * 64;   // LDS elem base for B frags

    // staging lane constants: wave w covers tile rows [w*32, w*32+32) in 4 segs
    const int ce = (((l & 7) ^ ((l >> 3) & 7)) << 3);  // inverse-swizzled col
    const unsigned short* Ag = A + (size_t)(m0 + w * 32 + (l >> 3)) * lda + ce;
    const unsigned short* Bg = B + (size_t)(n0 + w * 32 + (l >> 3)) * ldb + ce;

    f32x4 acc[8][4] = {};
    const int NP = K >> 6;  // BK=64 pairs

    // prologue: stage pair 0 into buf 0
#pragma unroll
    for (int j = 0; j < 4; ++j) {
        gld16(Ag + (size_t)(j * 8) * lda, &lds[w * 2048 + j * 512]);
        gld16(Bg + (size_t)(j * 8) * ldb, &lds[32768 + w * 2048 + j * 512]);
    }
    asm volatile("s_waitcnt vmcnt(0)" ::: "memory");
    __builtin_amdgcn_s_barrier();

    for (int P = 0; P < NP; ++P) {
        const unsigned short* as = &lds[(P & 1) * 16384];
        const unsigned short* bs = &lds[32768 + (P & 1) * 16384];
        unsigned short* asn = &lds[((P + 1) & 1) * 16384];
        unsigned short* bsn = &lds[32768 + ((P + 1) & 1) * 16384];
        const bool st = (P + 1) < NP;
        const unsigned short* Agn = Ag + ((P + 1) << 6);
        const unsigned short* Bgn = Bg + ((P + 1) << 6);

#pragma unroll
        for (int sg = 0; sg < 2; ++sg) {  // two K=32 sub-tiles of the pair
            const int jb = ((sg * 4 + kslot) ^ jc) * 8;
            bf16x8 a[4], b[4];
            // phase (sg, mh=0): read A mi0-3 + B ni0-3; bunch-stage next pair on sg==0
#pragma unroll
            for (int i = 0; i < 4; ++i) {
                u16x8 v = *(const u16x8*)(as + arow + i * 1024 + jb);
                a[i] = __builtin_bit_cast(bf16x8, v);
            }
#pragma unroll
            for (int i = 0; i < 4; ++i) {
                u16x8 v = *(const u16x8*)(bs + brow + i * 1024 + jb);
                b[i] = __builtin_bit_cast(bf16x8, v);
            }
            if (sg == 0 && st) {
#pragma unroll
                for (int j = 0; j < 4; ++j) {
                    gld16(Agn + (size_t)(j * 8) * lda, asn + w * 2048 + j * 512);
                    gld16(Bgn + (size_t)(j * 8) * ldb, bsn + w * 2048 + j * 512);
                }
            }
            __builtin_amdgcn_s_barrier();
            __builtin_amdgcn_s_setprio(1);
#pragma unroll
            for (int i = 0; i < 4; ++i)
#pragma unroll
                for (int n = 0; n < 4; ++n)
                    acc[i][n] = __builtin_amdgcn_mfma_f32_16x16x32_bf16(a[i], b[n], acc[i][n], 0, 0, 0);
            __builtin_amdgcn_s_setprio(0);
            __builtin_amdgcn_s_barrier();
            // phase (sg, mh=1): read A mi4-7 (B reused in regs)
#pragma unroll
            for (int i = 0; i < 4; ++i) {
                u16x8 v = *(const u16x8*)(as + arow + 4096 + i * 1024 + jb);
                a[i] = __builtin_bit_cast(bf16x8, v);
            }
            __builtin_amdgcn_s_barrier();
            __builtin_amdgcn_s_setprio(1);
#pragma unroll
            for (int i = 0; i < 4; ++i)
#pragma unroll
                for (int n = 0; n < 4; ++n)
                    acc[4 + i][n] = __builtin_amdgcn_mfma_f32_16x16x32_bf16(a[i], b[n], acc[4 + i][n], 0, 0, 0);
            __builtin_amdgcn_s_setprio(0);
            if (sg == 1)  // pair boundary: drain our staging loads (counted: once/64K)
                asm volatile("s_waitcnt vmcnt(0)" ::: "memory");
            __builtin_amdgcn_s_barrier();
        }
    }

    // epilogue: C/D layout col=lane&15, row=(lane>>4)*4+rr [m89-verified]
#pragma unroll
    for (int mi = 0; mi < 8; ++mi) {
        int row = m0 + wm * 128 + mi * 16 + kslot * 4;
#pragma unroll
        for (int n = 0; n < 4; ++n) {
            int col = n0 + wn * 64 + n * 16 + lrow;
#pragma unroll
            for (int rr = 0; rr < 4; ++rr) {
                float v = acc[mi][n][rr] * scale;
                if constexpr (POLY) v = v * v + v;
                C[(size_t)(row + rr) * ldc + col] = f2bf(v);
            }
        }
    }
}

extern "C" void kernel_launch(void* const* d_in, const int* in_sizes, int n_in,
                              void* d_out, int out_size, void* d_ws, size_t ws_size,
                              hipStream_t stream) {
    const float* x  = (const float*)d_in[0];  // [2,4096,768]
    const float* Wq = (const float*)d_in[1];  // [768,768]
    const float* Wk = (const float*)d_in[2];
    const float* Wv = (const float*)d_in[3];
    const float* Wo = (const float*)d_in[4];
    float* out = (float*)d_out;

    const int BS = 8192, S = 4096, D = 768, D2 = 1536;
    const long long SD = (long long)S * D, SS = (long long)S * S;
    unsigned short* ws = (unsigned short*)d_ws;
    size_t o = 0;
    unsigned short* QK   = ws + o; o += (size_t)BS * D2;  // [8192][1536] = [Q|K]
    unsigned short* VWt  = ws + o; o += (size_t)BS * D;   // [768][8192]
    unsigned short* Wqkb = ws + o; o += (size_t)D2 * D;
    unsigned short* Wob  = ws + o; o += (size_t)D * D;
    unsigned short* WvT  = ws + o; o += (size_t)D * D;
    unsigned short* Wovb = ws + o; o += (size_t)D * D;
    unsigned short* xb   = ws + o;                        // dead after projections
    unsigned short* P    = xb;                            // P overlaps xb
    const size_t oxb = o;

    const bool batched = ws_size >= (oxb + 2ull * SS) * 2ull;

    // allow 128 KB dynamic LDS for the phased QK^T kernel
    static int lds_ok = 0;
    if (!lds_ok) {
        hipFuncSetAttribute((const void*)gemm_qkt8<true>,
                            hipFuncAttributeMaxDynamicSharedMemorySize, 131072);
        lds_ok = 1;
    }

    dim3 blk(256);
    cvt_f32_bf16<<<dim3(BS * D / 1024), blk, 0, stream>>>(x, xb, BS * D / 4);
    cvt3_f32_bf16<<<dim3(D * D / 1024, 3), blk, 0, stream>>>(
        Wq, Wk, Wo, Wqkb, Wqkb + (size_t)D * D, Wob, D * D / 4);
    cvt_t_f32_bf16<<<dim3(D / 32, D / 32), blk, 0, stream>>>(Wv, WvT, D);

    gemm_bt<128, false, unsigned short, false><<<dim3(6, 6, 1), blk, 0, stream>>>(
        Wob, WvT, Wovb, D, D, D, D, 1.0f, 0, 0, 0);
    gemm_proj2<<<dim3(1152), blk, 0, stream>>>(xb, Wqkb, QK, Wovb, VWt);

    if (batched) {
        // P = poly(1e-3 * Q @ K^T), both batches: 256^2 phased kernel
        gemm_qkt8<true><<<dim3(S / 256, S / 256, 2), dim3(512), 131072, stream>>>(
            QK, QK + D, P, D, D2, D2, S, 1e-3f,
            (long long)S * D2, (long long)S * D2, SS);
        // out = 0.1 * P @ VW  (M=4096, N=768, K=4096), fp32 out, full-K
        gemm_bt<64, false, float, true><<<dim3(D / 64, S / 128, 2), blk, 0, stream>>>(
            P, VWt, out, S, S, BS, D, 0.1f, SS, (long long)S, SD);
    } else {
        for (int b = 0; b < 2; ++b) {
            gemm_qkt8<true><<<dim3(S / 256, S / 256, 1), dim3(512), 131072, stream>>>(
                QK + (size_t)b * S * D2, QK + (size_t)b * S * D2 + D, P,
                D, D2, D2, S, 1e-3f, 0, 0, 0);
            gemm_bt<64, false, float, true><<<dim3(D / 64, S / 128, 1), blk, 0, stream>>>(
                P, VWt + (size_t)b * S, out + (size_t)b * SD, S, S, BS, D, 0.1f, 0, 0, 0);
        }
    }
}